// Round 2
// baseline (69.816 us; speedup 1.0000x reference)
//
#include <hip/hip_runtime.h>

// Problem constants (from reference): B=4, C=128, H=64, W=64, L=16, K=64, CD=8.
// C == L*CD. HW = H*W = 4096.
#define Bn   4
#define Cn   128
#define HWn  4096
#define Ln   16
#define Kn   64
#define CDn  8
#define QUANT_ELEMS (Bn * Cn * HWn)   // 2,097,152

typedef float floatx2 __attribute__((ext_vector_type(2)));
typedef float floatx4 __attribute__((ext_vector_type(4)));
typedef float floatx8 __attribute__((ext_vector_type(8)));

// One thread = one (b, l) slot x TWO adjacent pixels.
// Round-1 post-mortem: swapping LDS broadcasts for uniform global loads was
// NEUTRAL -> code-operand delivery is off the critical path. This round halves
// the kernel's instruction count with bit-identical arithmetic:
//   - 2 px/thread: dwordx2 z-loads/C-stores, each code vector loaded once
//     serves two distance computations.
//   - float2 packed math (__builtin_elementwise_fma -> v_pk_fma_f32 /
//     v_pk_add_f32): halves VALU issue for the sub+fma chain. Packed FMA is
//     IEEE-identical per component; per-pixel strict < with ascending k is
//     unchanged, so argmin decisions (and absmax=0.0) are preserved.
__global__ __launch_bounds__(256)
void soft_to_hard_encoder_kernel(const float* __restrict__ z,
                                 const float* __restrict__ codes,
                                 float* __restrict__ out) {
    // blockIdx.x = ((b*Ln + l) * 8) + pixblock ; 8 blocks x 256 thr x 2 px per (b,l)
    const int pixblock = blockIdx.x & 7;
    const int bl       = blockIdx.x >> 3;
    const int l        = bl & (Ln - 1);
    const int b        = bl >> 4;
    const int pix      = pixblock * 512 + threadIdx.x * 2;   // even -> 8B aligned

    // Wave-uniform base pointer to this latent slot's codes (64 x 8 floats, 2 KB,
    // L1/K$-resident).
    const float* __restrict__ cl = codes + (size_t)l * (Kn * CDn);

    // Load the 8-dim latent vectors for both pixels: dwordx2, lanes contiguous
    // -> 512B/instr coalesced.
    floatx2 hz[CDn];
    #pragma unroll
    for (int d = 0; d < CDn; ++d)
        hz[d] = *(const floatx2*)(z + (size_t)(b * Cn + l * CDn + d) * HWn + pix);

    // Argmin over 64 codes for both pixels. Strict < keeps the first (lowest k)
    // on ties, matching np.argmin. Distance math: packed sub + packed fma,
    // component-wise identical to the scalar version.
    floatx2 best = {3.402823466e+38f, 3.402823466e+38f};
    int bidx0 = 0, bidx1 = 0;
    #pragma unroll 4
    for (int k = 0; k < Kn; ++k) {
        const floatx8 c8 = *(const floatx8*)(cl + k * CDn);  // uniform 32B
        floatx2 s = {0.0f, 0.0f};
        #pragma unroll
        for (int d = 0; d < CDn; ++d) {
            const floatx2 cc = {c8[d], c8[d]};
            const floatx2 df = hz[d] - cc;                   // v_pk_add (neg mod)
            s = __builtin_elementwise_fma(df, df, s);        // v_pk_fma_f32
        }
        if (s.x < best.x) { best.x = s.x; bidx0 = k; }
        if (s.y < best.y) { best.y = s.y; bidx1 = k; }
    }

    // Winner-code gathers (codes L1-resident; two 16B loads per pixel).
    const floatx4 a0 = *(const floatx4*)(cl + bidx0 * CDn);
    const floatx4 a1 = *(const floatx4*)(cl + bidx0 * CDn + 4);
    const floatx4 c0 = *(const floatx4*)(cl + bidx1 * CDn);
    const floatx4 c1 = *(const floatx4*)(cl + bidx1 * CDn + 4);

    // Hard symbols back to NCHW: one dwordx2 per d, coalesced across lanes.
    #pragma unroll
    for (int d = 0; d < 4; ++d) {
        floatx2 w;
        w.x = a0[d]; w.y = c0[d];
        *(floatx2*)(out + (size_t)(b * Cn + l * CDn + d) * HWn + pix) = w;
        w.x = a1[d]; w.y = c1[d];
        *(floatx2*)(out + (size_t)(b * Cn + l * CDn + 4 + d) * HWn + pix) = w;
    }

    // idxes layout (b,h,w,l): offset after the quantized block; stored as float.
    out[QUANT_ELEMS + (size_t)(b * HWn + pix)     * Ln + l] = (float)bidx0;
    out[QUANT_ELEMS + (size_t)(b * HWn + pix + 1) * Ln + l] = (float)bidx1;
}

extern "C" void kernel_launch(void* const* d_in, const int* in_sizes, int n_in,
                              void* d_out, int out_size, void* d_ws, size_t ws_size,
                              hipStream_t stream) {
    const float* z     = (const float*)d_in[0];  // (4,128,64,64) fp32
    const float* codes = (const float*)d_in[1];  // (16,64,8) fp32
    float* out         = (float*)d_out;          // quantized (2,097,152) + idxes (262,144)

    const int total_threads = Bn * Ln * HWn / 2; // 131,072 (2 px/thread)
    const int blocks = total_threads / 256;      // 512
    soft_to_hard_encoder_kernel<<<blocks, 256, 0, stream>>>(z, codes, out);
}